// Round 2
// baseline (1812.998 us; speedup 1.0000x reference)
//
#include <hip/hip_runtime.h>
#include <hip/hip_bf16.h>

#define NNODES 10000
#define NEDGES 320000
#define ETOT   (NEDGES + NNODES)
#define NGRAPH 100
#define CH     250   // HEADS*OUT
#define HOUT   125
#define MPAD   10048 // 157 * 64
#define NTILE  157   // MPAD/64
#define KP0    352   // layer-0 K=336 padded
#define KP1    256   // layers 1-3 K=250 padded
#define HPAD   256   // hb16 row stride (bf16) -> 512B rows
#define ECAP   128   // bucket capacity per node
#define DCAPW  128   // per-wave LDS edge cache (== ECAP)
#define NBLK   1024  // 4 blocks/CU x 256 CU -- co-resident by construction
#define NTHR   256

typedef __attribute__((ext_vector_type(8))) short bf16x8;
typedef __attribute__((ext_vector_type(4))) float f32x4;

static __device__ __forceinline__ float bflo(unsigned int u){
  union{ unsigned int i; float f; } v; v.i = u << 16; return v.f;
}
static __device__ __forceinline__ float bfhi(unsigned int u){
  union{ unsigned int i; float f; } v; v.i = u & 0xffff0000u; return v.f;
}
static __device__ __forceinline__ unsigned short f2bfbits(float f){
  __hip_bfloat16 b = __float2bfloat16(f);
  union{ __hip_bfloat16 b; unsigned short s; } v; v.b = b; return v.s;
}

struct Args {
  const float* x; const int* eidx; const int* batch;
  const float *W0,*W1,*W2,*W3;
  const float *as_[4], *ad_[4], *bb[4];
  const float *lw1,*lb1,*lw2,*lb2,*lw3,*lb3,*lw4,*lb4;
  float* out;
  __hip_bfloat16 *hb16, *Abf0, *Abf, *Wt0, *Wt1, *Wt2, *Wt3;
  int *cursor, *bucket, *gstart;
  float *esA,*edA,*esB,*edB;
  int* bar;   // [0..255] per-group cnt (16 groups, 64B apart), [256] root, [320] gen
};

// ---- device-scope grid barrier: hierarchical, generation-counted, no resets ----
// Group g = blockIdx.x>>6 (64 blocks/group, 16 groups). Counters are cumulative:
// barrier bi complete when group cnt hits bi*64 and root hits bi*16; gen := bi.
// No reset -> no ABA race. Release/acquire via __threadfence + AGENT-scope atomics
// (cross-XCD safe, Guideline 16).
static __device__ __forceinline__ void gbar(int* bar, int bi){
  __syncthreads();
  if (threadIdx.x == 0){
    __threadfence();
    int g = (int)(blockIdx.x >> 6);
    if (atomicAdd(&bar[g * 16], 1) == bi * 64 - 1){
      if (atomicAdd(&bar[256], 1) == bi * 16 - 1){
        __threadfence();
        __hip_atomic_store(&bar[320], bi, __ATOMIC_RELEASE, __HIP_MEMORY_SCOPE_AGENT);
      }
    }
    while (__hip_atomic_load(&bar[320], __ATOMIC_ACQUIRE, __HIP_MEMORY_SCOPE_AGENT) < bi)
      __builtin_amdgcn_s_sleep(2);
    __threadfence();
  }
  __syncthreads();
}

// ---------------- phase 0: bucketed edge placement + gstart + xconv + wconv -----------
static __device__ void pre_phase(const Args& a){
  int gtid = blockIdx.x * NTHR + threadIdx.x;
  const int gstr = NBLK * NTHR;
  for (int e = gtid; e < ETOT; e += gstr){
    int dst, src;
    if (e < NEDGES){ src = a.eidx[e]; dst = a.eidx[NEDGES + e]; }
    else           { src = e - NEDGES; dst = src; }
    int pos = atomicAdd(&a.cursor[dst], 1);
    if (pos < ECAP) a.bucket[(size_t)dst * ECAP + pos] = src;
  }
  for (int n = gtid; n < NNODES; n += gstr){
    int b1 = a.batch[n];
    int b0 = (n == 0) ? -1 : a.batch[n-1];
    for (int b = b0 + 1; b <= b1; ++b) a.gstart[b] = n;
    if (n == NNODES - 1){
      for (int b = b1 + 1; b <= NGRAPH; ++b) a.gstart[b] = NNODES;
    }
  }
  // xconv: float4 in (rows are 16B aligned: 336*4 = 84*16), ushort4 out
  for (int j = gtid; j < NNODES * 84; j += gstr){
    int r = j / 84, c4 = (j - r * 84) * 4;
    float4 v = *(const float4*)(a.x + (size_t)r * 336 + c4);
    ushort4 o;
    o.x = f2bfbits(v.x); o.y = f2bfbits(v.y); o.z = f2bfbits(v.z); o.w = f2bfbits(v.w);
    *(ushort4*)(a.Abf0 + (size_t)r * KP0 + c4) = o;
  }
  const int T0 = 16 * KP0 * 16;
  const int T1 = 16 * KP1 * 16;
  int tot = T0 + 3*T1;
  for (int i = gtid; i < tot; i += gstr){
    const float* W; __hip_bfloat16* Wt; int K, Kp, li;
    if (i < T0)             { W = a.W0; Wt = a.Wt0; K = 336; Kp = KP0; li = i; }
    else if (i < T0 +   T1) { W = a.W1; Wt = a.Wt1; K = CH;  Kp = KP1; li = i - T0; }
    else if (i < T0 + 2*T1) { W = a.W2; Wt = a.Wt2; K = CH;  Kp = KP1; li = i - T0 - T1; }
    else                    { W = a.W3; Wt = a.Wt3; K = CH;  Kp = KP1; li = i - T0 - 2*T1; }
    int KC = Kp >> 5;
    int nt = li / (Kp * 16);
    int rem = li % (Kp * 16);
    int k = rem / 16;
    int n = rem % 16;
    int col = nt * 16 + n;
    float v = (k < K && col < CH) ? W[(size_t)k * CH + col] : 0.f;
    Wt[(((size_t)nt * KC + (k >> 5)) * 16 + n) * 32 + (k & 31)] = __float2bfloat16(v);
  }
}

// ---------------- MFMA GEMM + fused attention scores (tile t = blockIdx.x) ------------
static __device__ void gemm_phase(
    const __hip_bfloat16* __restrict__ A, const __hip_bfloat16* __restrict__ Wt,
    __hip_bfloat16* __restrict__ Cb, const float* __restrict__ asrc,
    const float* __restrict__ adst, float* __restrict__ esrc, float* __restrict__ edst,
    int Kp){
  int t = blockIdx.x;
  if (t >= NTILE * 4) return;
  int bx = t % NTILE, by = t / NTILE;
  int wv = threadIdx.x >> 6, lane = threadIdx.x & 63;
  int n16 = lane & 15, q = lane >> 4;
  int KC = Kp >> 5;
  int rowbase = bx * 64 + wv * 16;
  int bn = by * 64;
  int nt0 = bn >> 4;
  const __hip_bfloat16* ap = A  + (size_t)(rowbase + n16) * Kp + q * 8;
  const __hip_bfloat16* bp = Wt + ((size_t)nt0 * KC * 16 + n16) * 32 + q * 8;
  f32x4 ac0 = {0.f,0.f,0.f,0.f}, ac1 = ac0, ac2 = ac0, ac3 = ac0;
  for (int kc = 0; kc < KC; ++kc){
    bf16x8 av = *(const bf16x8*)(ap + (size_t)kc * 32);
    bf16x8 b0 = *(const bf16x8*)(bp + ((size_t)0 * KC + kc) * 512);
    bf16x8 b1 = *(const bf16x8*)(bp + ((size_t)1 * KC + kc) * 512);
    bf16x8 b2 = *(const bf16x8*)(bp + ((size_t)2 * KC + kc) * 512);
    bf16x8 b3 = *(const bf16x8*)(bp + ((size_t)3 * KC + kc) * 512);
    ac0 = __builtin_amdgcn_mfma_f32_16x16x32_bf16(av, b0, ac0, 0, 0, 0);
    ac1 = __builtin_amdgcn_mfma_f32_16x16x32_bf16(av, b1, ac1, 0, 0, 0);
    ac2 = __builtin_amdgcn_mfma_f32_16x16x32_bf16(av, b2, ac2, 0, 0, 0);
    ac3 = __builtin_amdgcn_mfma_f32_16x16x32_bf16(av, b3, ac3, 0, 0, 0);
  }
  float es0[4] = {}, es1[4] = {}, ed0a[4] = {}, ed1a[4] = {};
  #define SCORE_T(AC, T) { \
    int col = bn + (T)*16 + n16; \
    bool ok = col < CH; \
    float av_ = ok ? asrc[col] : 0.f; \
    float dv_ = ok ? adst[col] : 0.f; \
    bool hh = col >= HOUT; \
    float av0 = hh ? 0.f : av_, av1 = hh ? av_ : 0.f; \
    float dv0 = hh ? 0.f : dv_, dv1 = hh ? dv_ : 0.f; \
    _Pragma("unroll") \
    for (int r = 0; r < 4; ++r){ \
      es0[r] += AC[r]*av0; es1[r] += AC[r]*av1; \
      ed0a[r] += AC[r]*dv0; ed1a[r] += AC[r]*dv1; } }
  SCORE_T(ac0, 0) SCORE_T(ac1, 1) SCORE_T(ac2, 2) SCORE_T(ac3, 3)
  #undef SCORE_T
  #pragma unroll
  for (int off = 1; off < 16; off <<= 1){
    #pragma unroll
    for (int r = 0; r < 4; ++r){
      es0[r]  += __shfl_xor(es0[r],  off);
      es1[r]  += __shfl_xor(es1[r],  off);
      ed0a[r] += __shfl_xor(ed0a[r], off);
      ed1a[r] += __shfl_xor(ed1a[r], off);
    }
  }
  if (n16 == 0){
    #pragma unroll
    for (int r = 0; r < 4; ++r){
      int row = rowbase + q*4 + r;
      if (row < NNODES){
        atomicAdd(&esrc[row*2+0], es0[r]);
        atomicAdd(&esrc[row*2+1], es1[r]);
        atomicAdd(&edst[row*2+0], ed0a[r]);
        atomicAdd(&edst[row*2+1], ed1a[r]);
      }
    }
  }
  // zero-fill cols >= CH so the attn dwordx4 gather reads clean zeros
  #pragma unroll
  for (int r = 0; r < 4; ++r){
    int row = rowbase + q * 4 + r;
    if (row >= NNODES) continue;
    int col = bn + n16;
    __hip_bfloat16* cb = Cb + (size_t)row * HPAD + col;
    cb[0]  = __float2bfloat16(col      < CH ? ac0[r] : 0.f);
    cb[16] = __float2bfloat16(col + 16 < CH ? ac1[r] : 0.f);
    cb[32] = __float2bfloat16(col + 32 < CH ? ac2[r] : 0.f);
    cb[48] = __float2bfloat16(col + 48 < CH ? ac3[r] : 0.f);
  }
}

// ---------------- fused softmax + gather: wave per node (LDS slices wave-private, ------
// no __syncthreads -> waves drift freely). Phase B: half-waves own even/odd edges,
// 8 cols x dwordx4 per lane, 4 loads in flight per half-wave.
static __device__ void attn_phase(int (*s_src)[DCAPW], float2 (*s_x)[DCAPW],
                        const __hip_bfloat16* __restrict__ h,
                        const float* __restrict__ esrc, const float* __restrict__ edst,
                        const int* __restrict__ degv, const int* __restrict__ bucket,
                        const float* __restrict__ bias, __hip_bfloat16* __restrict__ outb,
                        float* __restrict__ esZ, float* __restrict__ edZ){
  int wv = threadIdx.x >> 6, lane = threadIdx.x & 63;
  int half = lane >> 5, hl = lane & 31;
  int c0 = hl * 8;
  int n0 = HOUT - c0; n0 = n0 < 0 ? 0 : (n0 > 8 ? 8 : n0);
  const __hip_bfloat16* __restrict__ hrow = h + c0;
  for (int grp = blockIdx.x; grp < NNODES/4; grp += NBLK){
    int node = grp * 4 + wv;
    int deg = degv[node]; if (deg > ECAP) deg = ECAP;
    const int* __restrict__ eb = bucket + (size_t)node * ECAP;
    float ed0 = edst[node*2+0], ed1 = edst[node*2+1];
    float sm0 = 0.f, sm1 = 0.f;
    for (int i = lane; i < deg; i += 64){
      int src = eb[i];
      float2 ev = *(const float2*)(esrc + (size_t)src * 2);
      float e0 = ev.x + ed0; e0 = e0 > 0.f ? e0 : 0.2f*e0;
      float e1 = ev.y + ed1; e1 = e1 > 0.f ? e1 : 0.2f*e1;
      float x0 = __expf(e0), x1 = __expf(e1);
      s_src[wv][i] = src; s_x[wv][i] = make_float2(x0, x1);
      sm0 += x0; sm1 += x1;
    }
    #pragma unroll
    for (int off = 32; off > 0; off >>= 1){
      sm0 += __shfl_xor(sm0, off);
      sm1 += __shfl_xor(sm1, off);
    }
    float inv0 = 1.f / (sm0 + 1e-16f);
    float inv1 = 1.f / (sm1 + 1e-16f);
    float acc[8] = {0.f,0.f,0.f,0.f,0.f,0.f,0.f,0.f};
    #define EDGE(IDX) { \
      bool vld = (IDX) < deg; \
      int jj = vld ? (IDX) : 0; \
      int s = s_src[wv][jj]; \
      float2 xv = s_x[wv][jj]; \
      float a0 = vld ? xv.x : 0.f; \
      float a1 = vld ? xv.y : 0.f; \
      uint4 d = *(const uint4*)(hrow + (size_t)s * HPAD); \
      acc[0] += (0 < n0 ? a0 : a1) * bflo(d.x); \
      acc[1] += (1 < n0 ? a0 : a1) * bfhi(d.x); \
      acc[2] += (2 < n0 ? a0 : a1) * bflo(d.y); \
      acc[3] += (3 < n0 ? a0 : a1) * bfhi(d.y); \
      acc[4] += (4 < n0 ? a0 : a1) * bflo(d.z); \
      acc[5] += (5 < n0 ? a0 : a1) * bfhi(d.z); \
      acc[6] += (6 < n0 ? a0 : a1) * bflo(d.w); \
      acc[7] += (7 < n0 ? a0 : a1) * bfhi(d.w); }
    for (int it = half; it < deg; it += 8){
      EDGE(it)
      EDGE(it + 2)
      EDGE(it + 4)
      EDGE(it + 6)
    }
    #undef EDGE
    #pragma unroll
    for (int j = 0; j < 8; ++j) acc[j] += __shfl_xor(acc[j], 32);
    if (half == 0){
      if (hl < 31){
        float4 bA = *(const float4*)&bias[c0];
        float4 bB = *(const float4*)&bias[c0 + 4];
        float v0 = acc[0]*(0 < n0 ? inv0 : inv1) + bA.x;
        float v1 = acc[1]*(1 < n0 ? inv0 : inv1) + bA.y;
        float v2 = acc[2]*(2 < n0 ? inv0 : inv1) + bA.z;
        float v3 = acc[3]*(3 < n0 ? inv0 : inv1) + bA.w;
        float v4 = acc[4]*(4 < n0 ? inv0 : inv1) + bB.x;
        float v5 = acc[5]*(5 < n0 ? inv0 : inv1) + bB.y;
        float v6 = acc[6]*(6 < n0 ? inv0 : inv1) + bB.z;
        float v7 = acc[7]*(7 < n0 ? inv0 : inv1) + bB.w;
        v0 = v0 > 0.f ? v0 : 0.f; v1 = v1 > 0.f ? v1 : 0.f;
        v2 = v2 > 0.f ? v2 : 0.f; v3 = v3 > 0.f ? v3 : 0.f;
        v4 = v4 > 0.f ? v4 : 0.f; v5 = v5 > 0.f ? v5 : 0.f;
        v6 = v6 > 0.f ? v6 : 0.f; v7 = v7 > 0.f ? v7 : 0.f;
        uint4 o;
        o.x = (unsigned int)f2bfbits(v0) | ((unsigned int)f2bfbits(v1) << 16);
        o.y = (unsigned int)f2bfbits(v2) | ((unsigned int)f2bfbits(v3) << 16);
        o.z = (unsigned int)f2bfbits(v4) | ((unsigned int)f2bfbits(v5) << 16);
        o.w = (unsigned int)f2bfbits(v6) | ((unsigned int)f2bfbits(v7) << 16);
        *(uint4*)(outb + (size_t)node * KP1 + c0) = o;
      } else {
        float v0 = acc[0]*inv1 + bias[248];      // cols 248,249 are head-1
        float v1 = acc[1]*inv1 + bias[249];
        v0 = v0 > 0.f ? v0 : 0.f; v1 = v1 > 0.f ? v1 : 0.f;
        unsigned int o = (unsigned int)f2bfbits(v0) | ((unsigned int)f2bfbits(v1) << 16);
        *(unsigned int*)(outb + (size_t)node * KP1 + 248) = o;
      }
    }
    if (lane < 2){   // prep next layer's score accumulators
      esZ[node*2 + lane] = 0.f;
      edZ[node*2 + lane] = 0.f;
    }
  }
}

// ---------------- head: segmented mean pool (bf16 input) + 4-layer MLP -----------------
static __device__ void head_phase(float* gvec, float* m1, float* m2, float* m3,
                        const __hip_bfloat16* __restrict__ xb,
                        const int* __restrict__ gstart,
                        const float* __restrict__ lw1, const float* __restrict__ lb1,
                        const float* __restrict__ lw2, const float* __restrict__ lb2,
                        const float* __restrict__ lw3, const float* __restrict__ lb3,
                        const float* __restrict__ lw4, const float* __restrict__ lb4,
                        float* __restrict__ out){
  int g = blockIdx.x;
  if (g >= NGRAPH) return;
  int tid = threadIdx.x;
  int s = gstart[g], e = gstart[g+1];
  if (tid < 128){
    int c2 = tid * 2;
    const __hip_bfloat16* xp = xb + c2;
    float a0=0.f,a1=0.f,b0=0.f,b1=0.f;
    int n = s;
    for (; n + 3 < e; n += 4){
      unsigned int u0 = *(const unsigned int*)(xp + (size_t)n     * KP1);
      unsigned int u1 = *(const unsigned int*)(xp + (size_t)(n+1) * KP1);
      unsigned int u2 = *(const unsigned int*)(xp + (size_t)(n+2) * KP1);
      unsigned int u3 = *(const unsigned int*)(xp + (size_t)(n+3) * KP1);
      a0 += bflo(u0) + bflo(u2); a1 += bfhi(u0) + bfhi(u2);
      b0 += bflo(u1) + bflo(u3); b1 += bfhi(u1) + bfhi(u3);
    }
    for (; n < e; ++n){
      unsigned int u0 = *(const unsigned int*)(xp + (size_t)n * KP1);
      a0 += bflo(u0); a1 += bfhi(u0);
    }
    float scale = 1.f / fmaxf((float)(e - s), 1.f);
    gvec[c2]     = (a0 + b0) * scale;
    gvec[c2 + 1] = (a1 + b1) * scale;
  }
  __syncthreads();
  if (tid < 200){
    float a0=0.f,a1=0.f,a2=0.f,a3=0.f;
    int k = 0;
    for (; k + 3 < CH; k += 4){
      a0 += gvec[k]   * lw1[(size_t)k     * 200 + tid];
      a1 += gvec[k+1] * lw1[(size_t)(k+1) * 200 + tid];
      a2 += gvec[k+2] * lw1[(size_t)(k+2) * 200 + tid];
      a3 += gvec[k+3] * lw1[(size_t)(k+3) * 200 + tid];
    }
    for (; k < CH; ++k) a0 += gvec[k] * lw1[(size_t)k * 200 + tid];
    float v = a0 + a1 + a2 + a3 + lb1[tid];
    m1[tid] = v > 0.f ? v : 0.f;
  }
  __syncthreads();
  if (tid < 100){
    float a0=0.f,a1=0.f,a2=0.f,a3=0.f;
    for (int k = 0; k + 3 < 200; k += 4){
      a0 += m1[k]   * lw2[(size_t)k     * 100 + tid];
      a1 += m1[k+1] * lw2[(size_t)(k+1) * 100 + tid];
      a2 += m1[k+2] * lw2[(size_t)(k+2) * 100 + tid];
      a3 += m1[k+3] * lw2[(size_t)(k+3) * 100 + tid];
    }
    float v = a0 + a1 + a2 + a3 + lb2[tid];
    m2[tid] = v > 0.f ? v : 0.f;
  }
  __syncthreads();
  if (tid < 100){
    float a0=0.f,a1=0.f,a2=0.f,a3=0.f;
    for (int k = 0; k + 3 < 100; k += 4){
      a0 += m2[k]   * lw3[(size_t)k     * 100 + tid];
      a1 += m2[k+1] * lw3[(size_t)(k+1) * 100 + tid];
      a2 += m2[k+2] * lw3[(size_t)(k+2) * 100 + tid];
      a3 += m2[k+3] * lw3[(size_t)(k+3) * 100 + tid];
    }
    float v = a0 + a1 + a2 + a3 + lb3[tid];
    m3[tid] = v > 0.f ? v : 0.f;
  }
  __syncthreads();
  if (tid < 29){
    float a0=0.f,a1=0.f,a2=0.f,a3=0.f;
    for (int k = 0; k + 3 < 100; k += 4){
      a0 += m3[k]   * lw4[(size_t)k     * 29 + tid];
      a1 += m3[k+1] * lw4[(size_t)(k+1) * 29 + tid];
      a2 += m3[k+2] * lw4[(size_t)(k+2) * 29 + tid];
      a3 += m3[k+3] * lw4[(size_t)(k+3) * 29 + tid];
    }
    out[(size_t)g * 29 + tid] = a0 + a1 + a2 + a3 + lb4[tid];
  }
}

// ---------------- the persistent mega-kernel: 9 grid barriers, 1 launch ----------------
__global__ __launch_bounds__(NTHR, 4) void k_all(Args a){
  __shared__ int    s_src[4][DCAPW];
  __shared__ float2 s_x[4][DCAPW];
  __shared__ float  gvec[256], m1[200], m2[112], m3[112];

  pre_phase(a);
  gbar(a.bar, 1);

  const __hip_bfloat16* Wts[4] = {a.Wt0, a.Wt1, a.Wt2, a.Wt3};
  int bi = 2;
  for (int L = 0; L < 4; ++L){
    int Kp = (L == 0) ? KP0 : KP1;
    const __hip_bfloat16* Ain = (L == 0) ? a.Abf0 : a.Abf;
    float* es  = (L & 1) ? a.esB : a.esA;
    float* ed  = (L & 1) ? a.edB : a.edA;
    float* esZ = (L & 1) ? a.esA : a.esB;
    float* edZ = (L & 1) ? a.edA : a.edB;

    gemm_phase(Ain, Wts[L], a.hb16, a.as_[L], a.ad_[L], es, ed, Kp);
    gbar(a.bar, bi++);
    attn_phase(s_src, s_x, a.hb16, es, ed, a.cursor, a.bucket, a.bb[L], a.Abf, esZ, edZ);
    gbar(a.bar, bi++);
  }

  head_phase(gvec, m1, m2, m3, a.Abf, a.gstart,
             a.lw1, a.lb1, a.lw2, a.lb2, a.lw3, a.lb3, a.lw4, a.lb4, a.out);
}

// ---------------- launch ----------------
extern "C" void kernel_launch(void* const* d_in, const int* in_sizes, int n_in,
                              void* d_out, int out_size, void* d_ws, size_t ws_size,
                              hipStream_t stream){
  char* ws = (char*)d_ws;
  size_t off = 0;
  auto alloc = [&](size_t bytes)->void*{
    void* p = ws + off;
    off = (off + bytes + 255) & ~(size_t)255;
    return p;
  };
  __hip_bfloat16* hb16 = (__hip_bfloat16*)alloc((size_t)NNODES * HPAD * 2);
  __hip_bfloat16* Abf0 = (__hip_bfloat16*)alloc((size_t)MPAD * KP0 * 2);
  __hip_bfloat16* Abf  = (__hip_bfloat16*)alloc((size_t)MPAD * KP1 * 2);
  __hip_bfloat16* Wt0  = (__hip_bfloat16*)alloc((size_t)16 * KP0 * 16 * 2);
  __hip_bfloat16* Wt1  = (__hip_bfloat16*)alloc((size_t)16 * KP1 * 16 * 2);
  __hip_bfloat16* Wt2  = (__hip_bfloat16*)alloc((size_t)16 * KP1 * 16 * 2);
  __hip_bfloat16* Wt3  = (__hip_bfloat16*)alloc((size_t)16 * KP1 * 16 * 2);
  size_t zbeg = off;
  int*   cursor = (int*)  alloc((size_t)NNODES * 4);      // doubles as deg
  float* esA  = (float*)alloc((size_t)NNODES * 2 * 4);
  float* edA  = (float*)alloc((size_t)NNODES * 2 * 4);
  int*   bar  = (int*)  alloc((size_t)384 * 4);           // barrier state (zeroed/launch)
  size_t zend = off;
  float* esB  = (float*)alloc((size_t)NNODES * 2 * 4);    // zeroed by attn L0
  float* edB  = (float*)alloc((size_t)NNODES * 2 * 4);
  int*   bucket = (int*)alloc((size_t)NNODES * ECAP * 4);
  int*   gstart = (int*)alloc((size_t)(NGRAPH + 1) * 4);

  hipMemsetAsync(ws + zbeg, 0, zend - zbeg, stream);

  Args a;
  a.x = (const float*)d_in[0];
  a.eidx = (const int*)d_in[1];
  a.batch = (const int*)d_in[2];
  a.W0 = (const float*)d_in[3];  a.W1 = (const float*)d_in[7];
  a.W2 = (const float*)d_in[11]; a.W3 = (const float*)d_in[15];
  for (int L = 0; L < 4; ++L){
    a.as_[L] = (const float*)d_in[4 + 4*L];
    a.ad_[L] = (const float*)d_in[5 + 4*L];
    a.bb[L]  = (const float*)d_in[6 + 4*L];
  }
  a.lw1 = (const float*)d_in[19]; a.lb1 = (const float*)d_in[20];
  a.lw2 = (const float*)d_in[21]; a.lb2 = (const float*)d_in[22];
  a.lw3 = (const float*)d_in[23]; a.lb3 = (const float*)d_in[24];
  a.lw4 = (const float*)d_in[25]; a.lb4 = (const float*)d_in[26];
  a.out = (float*)d_out;
  a.hb16 = hb16; a.Abf0 = Abf0; a.Abf = Abf;
  a.Wt0 = Wt0; a.Wt1 = Wt1; a.Wt2 = Wt2; a.Wt3 = Wt3;
  a.cursor = cursor; a.bucket = bucket; a.gstart = gstart;
  a.esA = esA; a.edA = edA; a.esB = esB; a.edB = edB;
  a.bar = bar;

  k_all<<<NBLK, NTHR, 0, stream>>>(a);
}

// Round 3
// 293.741 us; speedup vs baseline: 6.1721x; 6.1721x over previous
//
#include <hip/hip_runtime.h>
#include <hip/hip_bf16.h>

#define NNODES 10000
#define NEDGES 320000
#define ETOT   (NEDGES + NNODES)
#define NGRAPH 100
#define CH     250   // HEADS*OUT
#define HOUT   125
#define MPAD   10048 // 157 * 64
#define NTILE  157   // MPAD/64
#define KP0    352   // layer-0 K=336 padded
#define KP1    256   // layers 1-3 K=250 padded
#define HPAD   256   // hb16 row stride (bf16) -> 512B rows
#define ECAP   128   // bucket capacity per node: deg ~ 1+Poisson(32), +17 sigma; guarded
#define DCAPW  128   // per-wave LDS edge cache (== ECAP: cache always covers deg)

typedef __attribute__((ext_vector_type(8))) short bf16x8;
typedef __attribute__((ext_vector_type(4))) float f32x4;

static __device__ __forceinline__ float bflo(unsigned int u){
  union{ unsigned int i; float f; } v; v.i = u << 16; return v.f;
}
static __device__ __forceinline__ float bfhi(unsigned int u){
  union{ unsigned int i; float f; } v; v.i = u & 0xffff0000u; return v.f;
}
static __device__ __forceinline__ unsigned short f2bfbits(float f){
  __hip_bfloat16 b = __float2bfloat16(f);
  union{ __hip_bfloat16 b; unsigned short s; } v; v.b = b; return v.s;
}

struct Args {
  const float* x; const int* eidx; const int* batch;
  const float *W0,*W1,*W2,*W3;
  __hip_bfloat16 *hb16, *Abf0, *Abf, *Wt0, *Wt1, *Wt2, *Wt3;
  int *cursor; unsigned short* bucket; int *gstart;
};

// ---------------- pre: bucketed edge placement + gstart + xconv + wconv ----------------
__global__ void k_pre(Args a){
  int gtid = blockIdx.x * blockDim.x + threadIdx.x;
  int gstr = gridDim.x * blockDim.x;
  for (int e = gtid; e < ETOT; e += gstr){
    int dst, src;
    if (e < NEDGES){ src = a.eidx[e]; dst = a.eidx[NEDGES + e]; }
    else           { src = e - NEDGES; dst = src; }
    int pos = atomicAdd(&a.cursor[dst], 1);
    if (pos < ECAP) a.bucket[(size_t)dst * ECAP + pos] = (unsigned short)src;
  }
  for (int n = gtid; n < NNODES; n += gstr){
    int b1 = a.batch[n];
    int b0 = (n == 0) ? -1 : a.batch[n-1];
    for (int b = b0 + 1; b <= b1; ++b) a.gstart[b] = n;
    if (n == NNODES - 1){
      for (int b = b1 + 1; b <= NGRAPH; ++b) a.gstart[b] = NNODES;
    }
  }
  // xconv: float4 in (rows are 16B aligned: 336*4 = 84*16), ushort4 out
  for (int j = gtid; j < NNODES * 84; j += gstr){
    int r = j / 84, c4 = (j - r * 84) * 4;
    float4 v = *(const float4*)(a.x + (size_t)r * 336 + c4);
    ushort4 o;
    o.x = f2bfbits(v.x); o.y = f2bfbits(v.y); o.z = f2bfbits(v.z); o.w = f2bfbits(v.w);
    *(ushort4*)(a.Abf0 + (size_t)r * KP0 + c4) = o;
  }
  const int T0 = 16 * KP0 * 16;
  const int T1 = 16 * KP1 * 16;
  int tot = T0 + 3*T1;
  for (int i = gtid; i < tot; i += gstr){
    const float* W; __hip_bfloat16* Wt; int K, Kp, li;
    if (i < T0)             { W = a.W0; Wt = a.Wt0; K = 336; Kp = KP0; li = i; }
    else if (i < T0 +   T1) { W = a.W1; Wt = a.Wt1; K = CH;  Kp = KP1; li = i - T0; }
    else if (i < T0 + 2*T1) { W = a.W2; Wt = a.Wt2; K = CH;  Kp = KP1; li = i - T0 - T1; }
    else                    { W = a.W3; Wt = a.Wt3; K = CH;  Kp = KP1; li = i - T0 - 2*T1; }
    int KC = Kp >> 5;
    int nt = li / (Kp * 16);
    int rem = li % (Kp * 16);
    int k = rem / 16;
    int n = rem % 16;
    int col = nt * 16 + n;
    float v = (k < K && col < CH) ? W[(size_t)k * CH + col] : 0.f;
    Wt[(((size_t)nt * KC + (k >> 5)) * 16 + n) * 32 + (k & 31)] = __float2bfloat16(v);
  }
}

// ---------------- MFMA GEMM + fused attention scores ----------------
__global__ __launch_bounds__(256) void k_gemm(
    const __hip_bfloat16* __restrict__ A, const __hip_bfloat16* __restrict__ Wt,
    __hip_bfloat16* __restrict__ Cb, const float* __restrict__ asrc,
    const float* __restrict__ adst, float* __restrict__ esrc, float* __restrict__ edst,
    int Kp){
  int wv = threadIdx.x >> 6, lane = threadIdx.x & 63;
  int n16 = lane & 15, q = lane >> 4;
  int KC = Kp >> 5;
  int rowbase = blockIdx.x * 64 + wv * 16;
  int bn = blockIdx.y * 64;
  int nt0 = bn >> 4;
  const __hip_bfloat16* ap = A  + (size_t)(rowbase + n16) * Kp + q * 8;
  const __hip_bfloat16* bp = Wt + ((size_t)nt0 * KC * 16 + n16) * 32 + q * 8;
  f32x4 ac0 = {0.f,0.f,0.f,0.f}, ac1 = ac0, ac2 = ac0, ac3 = ac0;
  for (int kc = 0; kc < KC; ++kc){
    bf16x8 a  = *(const bf16x8*)(ap + (size_t)kc * 32);
    bf16x8 b0 = *(const bf16x8*)(bp + ((size_t)0 * KC + kc) * 512);
    bf16x8 b1 = *(const bf16x8*)(bp + ((size_t)1 * KC + kc) * 512);
    bf16x8 b2 = *(const bf16x8*)(bp + ((size_t)2 * KC + kc) * 512);
    bf16x8 b3 = *(const bf16x8*)(bp + ((size_t)3 * KC + kc) * 512);
    ac0 = __builtin_amdgcn_mfma_f32_16x16x32_bf16(a, b0, ac0, 0, 0, 0);
    ac1 = __builtin_amdgcn_mfma_f32_16x16x32_bf16(a, b1, ac1, 0, 0, 0);
    ac2 = __builtin_amdgcn_mfma_f32_16x16x32_bf16(a, b2, ac2, 0, 0, 0);
    ac3 = __builtin_amdgcn_mfma_f32_16x16x32_bf16(a, b3, ac3, 0, 0, 0);
  }
  float es0[4] = {}, es1[4] = {}, ed0a[4] = {}, ed1a[4] = {};
  #define SCORE_T(AC, T) { \
    int col = bn + (T)*16 + n16; \
    bool ok = col < CH; \
    float av = ok ? asrc[col] : 0.f; \
    float dv = ok ? adst[col] : 0.f; \
    bool hh = col >= HOUT; \
    float av0 = hh ? 0.f : av, av1 = hh ? av : 0.f; \
    float dv0 = hh ? 0.f : dv, dv1 = hh ? dv : 0.f; \
    _Pragma("unroll") \
    for (int r = 0; r < 4; ++r){ \
      es0[r] += AC[r]*av0; es1[r] += AC[r]*av1; \
      ed0a[r] += AC[r]*dv0; ed1a[r] += AC[r]*dv1; } }
  SCORE_T(ac0, 0) SCORE_T(ac1, 1) SCORE_T(ac2, 2) SCORE_T(ac3, 3)
  #undef SCORE_T
  #pragma unroll
  for (int off = 1; off < 16; off <<= 1){
    #pragma unroll
    for (int r = 0; r < 4; ++r){
      es0[r]  += __shfl_xor(es0[r],  off);
      es1[r]  += __shfl_xor(es1[r],  off);
      ed0a[r] += __shfl_xor(ed0a[r], off);
      ed1a[r] += __shfl_xor(ed1a[r], off);
    }
  }
  if (n16 == 0){
    #pragma unroll
    for (int r = 0; r < 4; ++r){
      int row = rowbase + q*4 + r;
      if (row < NNODES){
        atomicAdd(&esrc[row*2+0], es0[r]);
        atomicAdd(&esrc[row*2+1], es1[r]);
        atomicAdd(&edst[row*2+0], ed0a[r]);
        atomicAdd(&edst[row*2+1], ed1a[r]);
      }
    }
  }
  // zero-fill cols >= CH so k_attn's 8-col dwordx4 gather reads clean zeros
  #pragma unroll
  for (int r = 0; r < 4; ++r){
    int row = rowbase + q * 4 + r;
    if (row >= NNODES) continue;
    int col = bn + n16;
    __hip_bfloat16* cb = Cb + (size_t)row * HPAD + col;
    cb[0]  = __float2bfloat16(col      < CH ? ac0[r] : 0.f);
    cb[16] = __float2bfloat16(col + 16 < CH ? ac1[r] : 0.f);
    cb[32] = __float2bfloat16(col + 32 < CH ? ac2[r] : 0.f);
    cb[48] = __float2bfloat16(col + 48 < CH ? ac3[r] : 0.f);
  }
}

// ---------------- fused softmax + gather: wave per node, half-wave edge-parallel ------
// LDS slices are wave-private -> no __syncthreads; waves drift freely between phase A
// (exp/VALU) and phase B (gather/VMEM), mixing pipes across the block.
// Phase B: lanes 0-31 own cols [8h,8h+8) and walk even edges; lanes 32-63 walk odd
// edges over the same cols. 4 dwordx4 gathers in flight per half-wave.
__global__ __launch_bounds__(256) void k_attn(const __hip_bfloat16* __restrict__ h,
                        const float* __restrict__ esrc, const float* __restrict__ edst,
                        const int* __restrict__ degv, const unsigned short* __restrict__ bucket,
                        const float* __restrict__ bias, __hip_bfloat16* __restrict__ outb,
                        float* __restrict__ esZ, float* __restrict__ edZ){
  int wv = threadIdx.x >> 6, lane = threadIdx.x & 63;
  int node = blockIdx.x * 4 + wv;    // 2500 * 4 == NNODES exactly
  __shared__ int    s_src[4][DCAPW];
  __shared__ float2 s_x[4][DCAPW];
  int deg = degv[node]; if (deg > ECAP) deg = ECAP;
  const unsigned short* __restrict__ eb = bucket + (size_t)node * ECAP;
  float ed0 = edst[node*2+0], ed1 = edst[node*2+1];
  // phase A: exp(leaky(e)) -> LDS + wave sum  (deg <= ECAP == DCAPW, cache always covers)
  float sm0 = 0.f, sm1 = 0.f;
  for (int i = lane; i < deg; i += 64){
    int src = eb[i];
    float2 ev = *(const float2*)(esrc + (size_t)src * 2);
    float e0 = ev.x + ed0; e0 = e0 > 0.f ? e0 : 0.2f*e0;
    float e1 = ev.y + ed1; e1 = e1 > 0.f ? e1 : 0.2f*e1;
    float x0 = __expf(e0), x1 = __expf(e1);
    s_src[wv][i] = src; s_x[wv][i] = make_float2(x0, x1);
    sm0 += x0; sm1 += x1;
  }
  #pragma unroll
  for (int off = 32; off > 0; off >>= 1){
    sm0 += __shfl_xor(sm0, off);
    sm1 += __shfl_xor(sm1, off);
  }
  float inv0 = 1.f / (sm0 + 1e-16f);
  float inv1 = 1.f / (sm1 + 1e-16f);
  int half = lane >> 5, hl = lane & 31;
  int c0 = hl * 8;                       // 8 cols per lane; cols >= CH are zero in h
  int n0 = HOUT - c0; n0 = n0 < 0 ? 0 : (n0 > 8 ? 8 : n0);   // #head-0 cols of my 8
  const __hip_bfloat16* __restrict__ hrow = h + c0;
  float acc[8] = {0.f,0.f,0.f,0.f,0.f,0.f,0.f,0.f};
  #define EDGE(IDX) { \
    bool vld = (IDX) < deg; \
    int jj = vld ? (IDX) : 0; \
    int s = s_src[wv][jj]; \
    float2 xv = s_x[wv][jj]; \
    float a0 = vld ? xv.x : 0.f; \
    float a1 = vld ? xv.y : 0.f; \
    uint4 d = *(const uint4*)(hrow + (size_t)s * HPAD); \
    acc[0] += (0 < n0 ? a0 : a1) * bflo(d.x); \
    acc[1] += (1 < n0 ? a0 : a1) * bfhi(d.x); \
    acc[2] += (2 < n0 ? a0 : a1) * bflo(d.y); \
    acc[3] += (3 < n0 ? a0 : a1) * bfhi(d.y); \
    acc[4] += (4 < n0 ? a0 : a1) * bflo(d.z); \
    acc[5] += (5 < n0 ? a0 : a1) * bfhi(d.z); \
    acc[6] += (6 < n0 ? a0 : a1) * bflo(d.w); \
    acc[7] += (7 < n0 ? a0 : a1) * bfhi(d.w); }
  for (int it = half; it < deg; it += 8){
    EDGE(it)
    EDGE(it + 2)
    EDGE(it + 4)
    EDGE(it + 6)
  }
  #undef EDGE
  #pragma unroll
  for (int j = 0; j < 8; ++j) acc[j] += __shfl_xor(acc[j], 32);
  if (half == 0){
    if (hl < 31){
      float4 bA = *(const float4*)&bias[c0];
      float4 bB = *(const float4*)&bias[c0 + 4];
      float v0 = acc[0]*(0 < n0 ? inv0 : inv1) + bA.x;
      float v1 = acc[1]*(1 < n0 ? inv0 : inv1) + bA.y;
      float v2 = acc[2]*(2 < n0 ? inv0 : inv1) + bA.z;
      float v3 = acc[3]*(3 < n0 ? inv0 : inv1) + bA.w;
      float v4 = acc[4]*(4 < n0 ? inv0 : inv1) + bB.x;
      float v5 = acc[5]*(5 < n0 ? inv0 : inv1) + bB.y;
      float v6 = acc[6]*(6 < n0 ? inv0 : inv1) + bB.z;
      float v7 = acc[7]*(7 < n0 ? inv0 : inv1) + bB.w;
      v0 = v0 > 0.f ? v0 : 0.f; v1 = v1 > 0.f ? v1 : 0.f;
      v2 = v2 > 0.f ? v2 : 0.f; v3 = v3 > 0.f ? v3 : 0.f;
      v4 = v4 > 0.f ? v4 : 0.f; v5 = v5 > 0.f ? v5 : 0.f;
      v6 = v6 > 0.f ? v6 : 0.f; v7 = v7 > 0.f ? v7 : 0.f;
      uint4 o;
      o.x = (unsigned int)f2bfbits(v0) | ((unsigned int)f2bfbits(v1) << 16);
      o.y = (unsigned int)f2bfbits(v2) | ((unsigned int)f2bfbits(v3) << 16);
      o.z = (unsigned int)f2bfbits(v4) | ((unsigned int)f2bfbits(v5) << 16);
      o.w = (unsigned int)f2bfbits(v6) | ((unsigned int)f2bfbits(v7) << 16);
      *(uint4*)(outb + (size_t)node * KP1 + c0) = o;
    } else {
      float v0 = acc[0]*inv1 + bias[248];      // cols 248,249 are head-1
      float v1 = acc[1]*inv1 + bias[249];
      v0 = v0 > 0.f ? v0 : 0.f; v1 = v1 > 0.f ? v1 : 0.f;
      unsigned int o = (unsigned int)f2bfbits(v0) | ((unsigned int)f2bfbits(v1) << 16);
      *(unsigned int*)(outb + (size_t)node * KP1 + 248) = o;
    }
  }
  if (lane < 2){   // prep next layer's score accumulators
    esZ[node*2 + lane] = 0.f;
    edZ[node*2 + lane] = 0.f;
  }
}

// ---------------- fused head: segmented mean pool (bf16 input) + 4-layer MLP -------------
__global__ __launch_bounds__(256) void k_head(const __hip_bfloat16* __restrict__ xb,
                        const int* __restrict__ gstart,
                        const float* __restrict__ lw1, const float* __restrict__ lb1,
                        const float* __restrict__ lw2, const float* __restrict__ lb2,
                        const float* __restrict__ lw3, const float* __restrict__ lb3,
                        const float* __restrict__ lw4, const float* __restrict__ lb4,
                        float* __restrict__ out){
  int g = blockIdx.x;
  int tid = threadIdx.x;
  int s = gstart[g], e = gstart[g+1];
  __shared__ float gvec[256];
  __shared__ float m1[200];
  __shared__ float m2[112];
  __shared__ float m3[112];
  if (tid < 128){
    int c2 = tid * 2;                          // 2 bf16 cols per thread, 4B loads
    const __hip_bfloat16* xp = xb + c2;
    float a0=0.f,a1=0.f,b0=0.f,b1=0.f;
    int n = s;
    for (; n + 3 < e; n += 4){
      unsigned int u0 = *(const unsigned int*)(xp + (size_t)n     * KP1);
      unsigned int u1 = *(const unsigned int*)(xp + (size_t)(n+1) * KP1);
      unsigned int u2 = *(const unsigned int*)(xp + (size_t)(n+2) * KP1);
      unsigned int u3 = *(const unsigned int*)(xp + (size_t)(n+3) * KP1);
      a0 += bflo(u0) + bflo(u2); a1 += bfhi(u0) + bfhi(u2);
      b0 += bflo(u1) + bflo(u3); b1 += bfhi(u1) + bfhi(u3);
    }
    for (; n < e; ++n){
      unsigned int u0 = *(const unsigned int*)(xp + (size_t)n * KP1);
      a0 += bflo(u0); a1 += bfhi(u0);
    }
    float scale = 1.f / fmaxf((float)(e - s), 1.f);
    gvec[c2]     = (a0 + b0) * scale;
    gvec[c2 + 1] = (a1 + b1) * scale;
  }
  __syncthreads();
  if (tid < 200){
    float a0=0.f,a1=0.f,a2=0.f,a3=0.f;
    int k = 0;
    for (; k + 3 < CH; k += 4){
      a0 += gvec[k]   * lw1[(size_t)k     * 200 + tid];
      a1 += gvec[k+1] * lw1[(size_t)(k+1) * 200 + tid];
      a2 += gvec[k+2] * lw1[(size_t)(k+2) * 200 + tid];
      a3 += gvec[k+3] * lw1[(size_t)(k+3) * 200 + tid];
    }
    for (; k < CH; ++k) a0 += gvec[k] * lw1[(size_t)k * 200 + tid];
    float v = a0 + a1 + a2 + a3 + lb1[tid];
    m1[tid] = v > 0.f ? v : 0.f;
  }
  __syncthreads();
  if (tid < 100){
    float a0=0.f,a1=0.f,a2=0.f,a3=0.f;
    for (int k = 0; k + 3 < 200; k += 4){
      a0 += m1[k]   * lw2[(size_t)k     * 100 + tid];
      a1 += m1[k+1] * lw2[(size_t)(k+1) * 100 + tid];
      a2 += m1[k+2] * lw2[(size_t)(k+2) * 100 + tid];
      a3 += m1[k+3] * lw2[(size_t)(k+3) * 100 + tid];
    }
    float v = a0 + a1 + a2 + a3 + lb2[tid];
    m2[tid] = v > 0.f ? v : 0.f;
  }
  __syncthreads();
  if (tid < 100){
    float a0=0.f,a1=0.f,a2=0.f,a3=0.f;
    for (int k = 0; k + 3 < 100; k += 4){
      a0 += m2[k]   * lw3[(size_t)k     * 100 + tid];
      a1 += m2[k+1] * lw3[(size_t)(k+1) * 100 + tid];
      a2 += m2[k+2] * lw3[(size_t)(k+2) * 100 + tid];
      a3 += m2[k+3] * lw3[(size_t)(k+3) * 100 + tid];
    }
    float v = a0 + a1 + a2 + a3 + lb3[tid];
    m3[tid] = v > 0.f ? v : 0.f;
  }
  __syncthreads();
  if (tid < 29){
    float a0=0.f,a1=0.f,a2=0.f,a3=0.f;
    for (int k = 0; k + 3 < 100; k += 4){
      a0 += m3[k]   * lw4[(size_t)k     * 29 + tid];
      a1 += m3[k+1] * lw4[(size_t)(k+1) * 29 + tid];
      a2 += m3[k+2] * lw4[(size_t)(k+2) * 29 + tid];
      a3 += m3[k+3] * lw4[(size_t)(k+3) * 29 + tid];
    }
    out[(size_t)g * 29 + tid] = a0 + a1 + a2 + a3 + lb4[tid];
  }
}

// ---------------- launch ----------------
extern "C" void kernel_launch(void* const* d_in, const int* in_sizes, int n_in,
                              void* d_out, int out_size, void* d_ws, size_t ws_size,
                              hipStream_t stream){
  char* ws = (char*)d_ws;
  size_t off = 0;
  auto alloc = [&](size_t bytes)->void*{
    void* p = ws + off;
    off = (off + bytes + 255) & ~(size_t)255;
    return p;
  };
  __hip_bfloat16* hb16 = (__hip_bfloat16*)alloc((size_t)NNODES * HPAD * 2);
  __hip_bfloat16* Abf0 = (__hip_bfloat16*)alloc((size_t)MPAD * KP0 * 2);
  __hip_bfloat16* Abf  = (__hip_bfloat16*)alloc((size_t)MPAD * KP1 * 2);
  __hip_bfloat16* Wt0  = (__hip_bfloat16*)alloc((size_t)16 * KP0 * 16 * 2);
  __hip_bfloat16* Wt1  = (__hip_bfloat16*)alloc((size_t)16 * KP1 * 16 * 2);
  __hip_bfloat16* Wt2  = (__hip_bfloat16*)alloc((size_t)16 * KP1 * 16 * 2);
  __hip_bfloat16* Wt3  = (__hip_bfloat16*)alloc((size_t)16 * KP1 * 16 * 2);
  size_t zbeg = off;
  int*   cursor = (int*)  alloc((size_t)NNODES * 4);      // doubles as deg
  float* esA  = (float*)alloc((size_t)NNODES * 2 * 4);
  float* edA  = (float*)alloc((size_t)NNODES * 2 * 4);
  size_t zend = off;
  float* esB  = (float*)alloc((size_t)NNODES * 2 * 4);    // zeroed by attn L0
  float* edB  = (float*)alloc((size_t)NNODES * 2 * 4);
  unsigned short* bucket = (unsigned short*)alloc((size_t)NNODES * ECAP * 2);
  int*   gstart = (int*)alloc((size_t)(NGRAPH + 1) * 4);

  hipMemsetAsync(ws + zbeg, 0, zend - zbeg, stream);

  Args a;
  a.x = (const float*)d_in[0];
  a.eidx = (const int*)d_in[1];
  a.batch = (const int*)d_in[2];
  a.W0 = (const float*)d_in[3];  a.W1 = (const float*)d_in[7];
  a.W2 = (const float*)d_in[11]; a.W3 = (const float*)d_in[15];
  a.hb16 = hb16; a.Abf0 = Abf0; a.Abf = Abf;
  a.Wt0 = Wt0; a.Wt1 = Wt1; a.Wt2 = Wt2; a.Wt3 = Wt3;
  a.cursor = cursor; a.bucket = bucket; a.gstart = gstart;

  k_pre<<<(ETOT + 255)/256, 256, 0, stream>>>(a);

  const __hip_bfloat16* Wts[4] = {Wt0, Wt1, Wt2, Wt3};
  for (int L = 0; L < 4; ++L){
    const float* as_ = (const float*)d_in[4 + 4*L];
    const float* ad_ = (const float*)d_in[5 + 4*L];
    const float* bb  = (const float*)d_in[6 + 4*L];
    int Kp = (L == 0) ? KP0 : KP1;
    const __hip_bfloat16* Ain = (L == 0) ? Abf0 : Abf;
    float* es  = (L & 1) ? esB : esA;
    float* ed  = (L & 1) ? edB : edA;
    float* esZ = (L & 1) ? esA : esB;
    float* edZ = (L & 1) ? edA : edB;

    k_gemm<<<dim3(NTILE, 4), 256, 0, stream>>>(Ain, Wts[L], hb16, as_, ad_, es, ed, Kp);
    k_attn<<<NNODES/4, 256, 0, stream>>>(hb16, es, ed, cursor, bucket, bb, Abf, esZ, edZ);
  }

  k_head<<<NGRAPH, 256, 0, stream>>>(Abf, gstart,
      (const float*)d_in[19], (const float*)d_in[20],
      (const float*)d_in[21], (const float*)d_in[22],
      (const float*)d_in[23], (const float*)d_in[24],
      (const float*)d_in[25], (const float*)d_in[26],
      (float*)d_out);
}

// Round 4
// 293.274 us; speedup vs baseline: 6.1819x; 1.0016x over previous
//
#include <hip/hip_runtime.h>
#include <hip/hip_bf16.h>

#define NNODES 10000
#define NEDGES 320000
#define ETOT   (NEDGES + NNODES)
#define NGRAPH 100
#define CH     250   // HEADS*OUT
#define HOUT   125
#define MPAD   10048 // 157 * 64
#define NTILE  157   // MPAD/64
#define KP0    352   // layer-0 K=336 padded
#define KP1    256   // layers 1-3 K=250 padded
#define HPAD   256   // hb16 row stride (bf16) -> 512B rows
#define ECAP   128   // bucket capacity per node: deg ~ 1+Poisson(32), +17 sigma; guarded
#define DCAPW  128   // per-wave LDS edge cache (== ECAP: cache always covers deg)
#define APAD   264   // LDS A-tile row stride (shorts): 528B = 33*16, bank-friendly

typedef __attribute__((ext_vector_type(8))) short bf16x8;
typedef __attribute__((ext_vector_type(4))) float f32x4;

static __device__ __forceinline__ float bflo(unsigned int u){
  union{ unsigned int i; float f; } v; v.i = u << 16; return v.f;
}
static __device__ __forceinline__ float bfhi(unsigned int u){
  union{ unsigned int i; float f; } v; v.i = u & 0xffff0000u; return v.f;
}
static __device__ __forceinline__ unsigned short f2bfbits(float f){
  __hip_bfloat16 b = __float2bfloat16(f);
  union{ __hip_bfloat16 b; unsigned short s; } v; v.b = b; return v.s;
}

struct Args {
  const float* x; const int* eidx; const int* batch;
  const float *W0,*W1,*W2,*W3;
  __hip_bfloat16 *Abf0, *Wt0, *Wt1, *Wt2, *Wt3;
  int *cursor; unsigned short* bucket; int *gstart;
};

// ---------------- pre: bucketed edge placement + gstart + xconv + wconv ----------------
__global__ void k_pre(Args a){
  int gtid = blockIdx.x * blockDim.x + threadIdx.x;
  int gstr = gridDim.x * blockDim.x;
  for (int e = gtid; e < ETOT; e += gstr){
    int dst, src;
    if (e < NEDGES){ src = a.eidx[e]; dst = a.eidx[NEDGES + e]; }
    else           { src = e - NEDGES; dst = src; }
    int pos = atomicAdd(&a.cursor[dst], 1);
    if (pos < ECAP) a.bucket[(size_t)dst * ECAP + pos] = (unsigned short)src;
  }
  for (int n = gtid; n < NNODES; n += gstr){
    int b1 = a.batch[n];
    int b0 = (n == 0) ? -1 : a.batch[n-1];
    for (int b = b0 + 1; b <= b1; ++b) a.gstart[b] = n;
    if (n == NNODES - 1){
      for (int b = b1 + 1; b <= NGRAPH; ++b) a.gstart[b] = NNODES;
    }
  }
  // xconv: float4 in (rows are 16B aligned: 336*4 = 84*16), ushort4 out
  for (int j = gtid; j < NNODES * 84; j += gstr){
    int r = j / 84, c4 = (j - r * 84) * 4;
    float4 v = *(const float4*)(a.x + (size_t)r * 336 + c4);
    ushort4 o;
    o.x = f2bfbits(v.x); o.y = f2bfbits(v.y); o.z = f2bfbits(v.z); o.w = f2bfbits(v.w);
    *(ushort4*)(a.Abf0 + (size_t)r * KP0 + c4) = o;
  }
  const int T0 = 16 * KP0 * 16;
  const int T1 = 16 * KP1 * 16;
  int tot = T0 + 3*T1;
  for (int i = gtid; i < tot; i += gstr){
    const float* W; __hip_bfloat16* Wt; int K, Kp, li;
    if (i < T0)             { W = a.W0; Wt = a.Wt0; K = 336; Kp = KP0; li = i; }
    else if (i < T0 +   T1) { W = a.W1; Wt = a.Wt1; K = CH;  Kp = KP1; li = i - T0; }
    else if (i < T0 + 2*T1) { W = a.W2; Wt = a.Wt2; K = CH;  Kp = KP1; li = i - T0 - T1; }
    else                    { W = a.W3; Wt = a.Wt3; K = CH;  Kp = KP1; li = i - T0 - 2*T1; }
    int KC = Kp >> 5;
    int nt = li / (Kp * 16);
    int rem = li % (Kp * 16);
    int k = rem / 16;
    int n = rem % 16;
    int col = nt * 16 + n;
    float v = (k < K && col < CH) ? W[(size_t)k * CH + col] : 0.f;
    Wt[(((size_t)nt * KC + (k >> 5)) * 16 + n) * 32 + (k & 31)] = __float2bfloat16(v);
  }
}

// ---------------- layer-0 MFMA GEMM + fused attention scores (atomics) ----------------
__global__ __launch_bounds__(256) void k_gemm(
    const __hip_bfloat16* __restrict__ A, const __hip_bfloat16* __restrict__ Wt,
    __hip_bfloat16* __restrict__ Cb, const float* __restrict__ asrc,
    const float* __restrict__ adst, float* __restrict__ esrc, float* __restrict__ edst,
    int Kp){
  int wv = threadIdx.x >> 6, lane = threadIdx.x & 63;
  int n16 = lane & 15, q = lane >> 4;
  int KC = Kp >> 5;
  int rowbase = blockIdx.x * 64 + wv * 16;
  int bn = blockIdx.y * 64;
  int nt0 = bn >> 4;
  const __hip_bfloat16* ap = A  + (size_t)(rowbase + n16) * Kp + q * 8;
  const __hip_bfloat16* bp = Wt + ((size_t)nt0 * KC * 16 + n16) * 32 + q * 8;
  f32x4 ac0 = {0.f,0.f,0.f,0.f}, ac1 = ac0, ac2 = ac0, ac3 = ac0;
  for (int kc = 0; kc < KC; ++kc){
    bf16x8 a  = *(const bf16x8*)(ap + (size_t)kc * 32);
    bf16x8 b0 = *(const bf16x8*)(bp + ((size_t)0 * KC + kc) * 512);
    bf16x8 b1 = *(const bf16x8*)(bp + ((size_t)1 * KC + kc) * 512);
    bf16x8 b2 = *(const bf16x8*)(bp + ((size_t)2 * KC + kc) * 512);
    bf16x8 b3 = *(const bf16x8*)(bp + ((size_t)3 * KC + kc) * 512);
    ac0 = __builtin_amdgcn_mfma_f32_16x16x32_bf16(a, b0, ac0, 0, 0, 0);
    ac1 = __builtin_amdgcn_mfma_f32_16x16x32_bf16(a, b1, ac1, 0, 0, 0);
    ac2 = __builtin_amdgcn_mfma_f32_16x16x32_bf16(a, b2, ac2, 0, 0, 0);
    ac3 = __builtin_amdgcn_mfma_f32_16x16x32_bf16(a, b3, ac3, 0, 0, 0);
  }
  float es0[4] = {}, es1[4] = {}, ed0a[4] = {}, ed1a[4] = {};
  #define SCORE_T(AC, T) { \
    int col = bn + (T)*16 + n16; \
    bool ok = col < CH; \
    float av = ok ? asrc[col] : 0.f; \
    float dv = ok ? adst[col] : 0.f; \
    bool hh = col >= HOUT; \
    float av0 = hh ? 0.f : av, av1 = hh ? av : 0.f; \
    float dv0 = hh ? 0.f : dv, dv1 = hh ? dv : 0.f; \
    _Pragma("unroll") \
    for (int r = 0; r < 4; ++r){ \
      es0[r] += AC[r]*av0; es1[r] += AC[r]*av1; \
      ed0a[r] += AC[r]*dv0; ed1a[r] += AC[r]*dv1; } }
  SCORE_T(ac0, 0) SCORE_T(ac1, 1) SCORE_T(ac2, 2) SCORE_T(ac3, 3)
  #undef SCORE_T
  #pragma unroll
  for (int off = 1; off < 16; off <<= 1){
    #pragma unroll
    for (int r = 0; r < 4; ++r){
      es0[r]  += __shfl_xor(es0[r],  off);
      es1[r]  += __shfl_xor(es1[r],  off);
      ed0a[r] += __shfl_xor(ed0a[r], off);
      ed1a[r] += __shfl_xor(ed1a[r], off);
    }
  }
  if (n16 == 0){
    #pragma unroll
    for (int r = 0; r < 4; ++r){
      int row = rowbase + q*4 + r;
      if (row < NNODES){
        atomicAdd(&esrc[row*2+0], es0[r]);
        atomicAdd(&esrc[row*2+1], es1[r]);
        atomicAdd(&edst[row*2+0], ed0a[r]);
        atomicAdd(&edst[row*2+1], ed1a[r]);
      }
    }
  }
  // zero-fill cols >= CH so the attn dwordx4 gather reads clean zeros
  #pragma unroll
  for (int r = 0; r < 4; ++r){
    int row = rowbase + q * 4 + r;
    if (row >= NNODES) continue;
    int col = bn + n16;
    __hip_bfloat16* cb = Cb + (size_t)row * HPAD + col;
    cb[0]  = __float2bfloat16(col      < CH ? ac0[r] : 0.f);
    cb[16] = __float2bfloat16(col + 16 < CH ? ac1[r] : 0.f);
    cb[32] = __float2bfloat16(col + 32 < CH ? ac2[r] : 0.f);
    cb[48] = __float2bfloat16(col + 48 < CH ? ac3[r] : 0.f);
  }
}

// ---------------- fused: attn(layer L-1) -> LDS tile -> GEMM(W_L) + scores ------------
// Block = 16 nodes, 16 waves (wave = node). Attn output never round-trips to global:
// it lands in a padded LDS A-tile, then 16 waves MFMA it against Wt (hot in L2).
// Scores for layer L are full-row per block -> plain stores, no atomics, no zero-init.
__global__ __launch_bounds__(1024, 8) void k_fused(
    const __hip_bfloat16* __restrict__ hcur,
    const float* __restrict__ esrc, const float* __restrict__ edst,
    const int* __restrict__ degv, const unsigned short* __restrict__ bucket,
    const float* __restrict__ bias,            // layer L-1 attn bias
    const __hip_bfloat16* __restrict__ Wt,     // layer L weights (tiled)
    const float* __restrict__ asrc, const float* __restrict__ adst, // layer L
    __hip_bfloat16* __restrict__ hnext,
    float* __restrict__ esN, float* __restrict__ edN){
  int w = threadIdx.x >> 6, lane = threadIdx.x & 63;
  int nodebase = blockIdx.x * 16;
  int node = nodebase + w;                      // 625 * 16 == NNODES exactly
  __shared__ unsigned short s_src[16][DCAPW];   // 4 KB
  __shared__ float2 s_x[16][DCAPW];             // 16 KB
  __shared__ short  h_lds[16][APAD];            // 8.25 KB  (A-tile, bf16 bits)
  __shared__ float  esp[16][16][2];             // 2 KB  per-wave col-stripe partials
  __shared__ float  edp[16][16][2];             // 2 KB
  // ---------- attn phase (wave-private, no block sync needed until tile done) ----------
  int deg = degv[node]; if (deg > ECAP) deg = ECAP;
  const unsigned short* __restrict__ eb = bucket + (size_t)node * ECAP;
  float ed0 = edst[node*2+0], ed1 = edst[node*2+1];
  float sm0 = 0.f, sm1 = 0.f;
  for (int i = lane; i < deg; i += 64){
    int src = eb[i];
    float2 ev = *(const float2*)(esrc + (size_t)src * 2);
    float e0 = ev.x + ed0; e0 = e0 > 0.f ? e0 : 0.2f*e0;
    float e1 = ev.y + ed1; e1 = e1 > 0.f ? e1 : 0.2f*e1;
    float x0 = __expf(e0), x1 = __expf(e1);
    s_src[w][i] = (unsigned short)src; s_x[w][i] = make_float2(x0, x1);
    sm0 += x0; sm1 += x1;
  }
  #pragma unroll
  for (int off = 32; off > 0; off >>= 1){
    sm0 += __shfl_xor(sm0, off);
    sm1 += __shfl_xor(sm1, off);
  }
  float inv0 = 1.f / (sm0 + 1e-16f);
  float inv1 = 1.f / (sm1 + 1e-16f);
  int half = lane >> 5, hl = lane & 31;
  int c0 = hl * 8;
  int n0 = HOUT - c0; n0 = n0 < 0 ? 0 : (n0 > 8 ? 8 : n0);
  const __hip_bfloat16* __restrict__ hrow = hcur + c0;
  float acc[8] = {0.f,0.f,0.f,0.f,0.f,0.f,0.f,0.f};
  #define EDGE(IDX) { \
    bool vld = (IDX) < deg; \
    int jj = vld ? (IDX) : 0; \
    int s = s_src[w][jj]; \
    float2 xv = s_x[w][jj]; \
    float a0 = vld ? xv.x : 0.f; \
    float a1 = vld ? xv.y : 0.f; \
    uint4 d = *(const uint4*)(hrow + (size_t)s * HPAD); \
    acc[0] += (0 < n0 ? a0 : a1) * bflo(d.x); \
    acc[1] += (1 < n0 ? a0 : a1) * bfhi(d.x); \
    acc[2] += (2 < n0 ? a0 : a1) * bflo(d.y); \
    acc[3] += (3 < n0 ? a0 : a1) * bfhi(d.y); \
    acc[4] += (4 < n0 ? a0 : a1) * bflo(d.z); \
    acc[5] += (5 < n0 ? a0 : a1) * bfhi(d.z); \
    acc[6] += (6 < n0 ? a0 : a1) * bflo(d.w); \
    acc[7] += (7 < n0 ? a0 : a1) * bfhi(d.w); }
  for (int it = half; it < deg; it += 8){
    EDGE(it)
    EDGE(it + 2)
    EDGE(it + 4)
    EDGE(it + 6)
  }
  #undef EDGE
  #pragma unroll
  for (int j = 0; j < 8; ++j) acc[j] += __shfl_xor(acc[j], 32);
  if (half == 0){
    if (hl < 31){
      float4 bA = *(const float4*)&bias[c0];
      float4 bB = *(const float4*)&bias[c0 + 4];
      float v0 = acc[0]*(0 < n0 ? inv0 : inv1) + bA.x;
      float v1 = acc[1]*(1 < n0 ? inv0 : inv1) + bA.y;
      float v2 = acc[2]*(2 < n0 ? inv0 : inv1) + bA.z;
      float v3 = acc[3]*(3 < n0 ? inv0 : inv1) + bA.w;
      float v4 = acc[4]*(4 < n0 ? inv0 : inv1) + bB.x;
      float v5 = acc[5]*(5 < n0 ? inv0 : inv1) + bB.y;
      float v6 = acc[6]*(6 < n0 ? inv0 : inv1) + bB.z;
      float v7 = acc[7]*(7 < n0 ? inv0 : inv1) + bB.w;
      v0 = v0 > 0.f ? v0 : 0.f; v1 = v1 > 0.f ? v1 : 0.f;
      v2 = v2 > 0.f ? v2 : 0.f; v3 = v3 > 0.f ? v3 : 0.f;
      v4 = v4 > 0.f ? v4 : 0.f; v5 = v5 > 0.f ? v5 : 0.f;
      v6 = v6 > 0.f ? v6 : 0.f; v7 = v7 > 0.f ? v7 : 0.f;
      uint4 o;
      o.x = (unsigned int)f2bfbits(v0) | ((unsigned int)f2bfbits(v1) << 16);
      o.y = (unsigned int)f2bfbits(v2) | ((unsigned int)f2bfbits(v3) << 16);
      o.z = (unsigned int)f2bfbits(v4) | ((unsigned int)f2bfbits(v5) << 16);
      o.w = (unsigned int)f2bfbits(v6) | ((unsigned int)f2bfbits(v7) << 16);
      *(uint4*)&h_lds[w][hl*8] = o;
    } else {
      float v0 = acc[0]*inv1 + bias[248];      // cols 248,249 are head-1
      float v1 = acc[1]*inv1 + bias[249];
      v0 = v0 > 0.f ? v0 : 0.f; v1 = v1 > 0.f ? v1 : 0.f;
      uint4 o;                                  // zero cols 250..255 (NaN x 0 hazard)
      o.x = (unsigned int)f2bfbits(v0) | ((unsigned int)f2bfbits(v1) << 16);
      o.y = 0u; o.z = 0u; o.w = 0u;
      *(uint4*)&h_lds[w][248] = o;
    }
  }
  __syncthreads();
  // ---------- GEMM phase: wave w owns col-tile w (cols w*16 .. w*16+15) ----------
  int n16 = lane & 15, q = lane >> 4;
  const int KC = KP1 >> 5;                       // 8
  const __hip_bfloat16* bp = Wt + ((size_t)w * KC * 16 + n16) * 32 + q * 8;
  const short* ap = &h_lds[n16][q * 8];
  f32x4 ac = {0.f,0.f,0.f,0.f};
  #pragma unroll
  for (int kc = 0; kc < KC; ++kc){
    bf16x8 av = *(const bf16x8*)(ap + kc * 32);
    bf16x8 bv = *(const bf16x8*)(bp + (size_t)kc * 512);
    ac = __builtin_amdgcn_mfma_f32_16x16x32_bf16(av, bv, ac, 0, 0, 0);
  }
  int col = w * 16 + n16;
  bool ok = col < CH;
  float av_ = ok ? asrc[col] : 0.f;
  float dv_ = ok ? adst[col] : 0.f;
  bool hh = col >= HOUT;
  float av0 = hh ? 0.f : av_, av1 = hh ? av_ : 0.f;
  float dv0 = hh ? 0.f : dv_, dv1 = hh ? dv_ : 0.f;
  float es0[4], es1[4], edd0[4], edd1[4];
  #pragma unroll
  for (int r = 0; r < 4; ++r){
    es0[r] = ac[r]*av0; es1[r] = ac[r]*av1;
    edd0[r] = ac[r]*dv0; edd1[r] = ac[r]*dv1;
  }
  #pragma unroll
  for (int off = 1; off < 16; off <<= 1){
    #pragma unroll
    for (int r = 0; r < 4; ++r){
      es0[r]  += __shfl_xor(es0[r],  off);
      es1[r]  += __shfl_xor(es1[r],  off);
      edd0[r] += __shfl_xor(edd0[r], off);
      edd1[r] += __shfl_xor(edd1[r], off);
    }
  }
  if (n16 == 0){
    #pragma unroll
    for (int r = 0; r < 4; ++r){
      esp[w][q*4+r][0] = es0[r];  esp[w][q*4+r][1] = es1[r];
      edp[w][q*4+r][0] = edd0[r]; edp[w][q*4+r][1] = edd1[r];
    }
  }
  // hnext write: zero-fill cols >= CH for next gather
  #pragma unroll
  for (int r = 0; r < 4; ++r){
    int row = nodebase + q*4 + r;
    hnext[(size_t)row * HPAD + col] = __float2bfloat16(ok ? ac[r] : 0.f);
  }
  __syncthreads();
  int t = threadIdx.x;
  if (t < 64){
    int row = t >> 2;
    int he = t & 1;
    int which = (t >> 1) & 1;
    float s = 0.f;
    #pragma unroll
    for (int w2 = 0; w2 < 16; ++w2)
      s += which ? edp[w2][row][he] : esp[w2][row][he];
    (which ? edN : esN)[(size_t)(nodebase + row) * 2 + he] = s;
  }
}

// ---------------- final softmax + gather: wave per node (feeds k_head) -----------------
__global__ __launch_bounds__(256) void k_attn(const __hip_bfloat16* __restrict__ h,
                        const float* __restrict__ esrc, const float* __restrict__ edst,
                        const int* __restrict__ degv, const unsigned short* __restrict__ bucket,
                        const float* __restrict__ bias, __hip_bfloat16* __restrict__ outb){
  int wv = threadIdx.x >> 6, lane = threadIdx.x & 63;
  int node = blockIdx.x * 4 + wv;    // 2500 * 4 == NNODES exactly
  __shared__ unsigned short s_src[4][DCAPW];
  __shared__ float2 s_x[4][DCAPW];
  int deg = degv[node]; if (deg > ECAP) deg = ECAP;
  const unsigned short* __restrict__ eb = bucket + (size_t)node * ECAP;
  float ed0 = edst[node*2+0], ed1 = edst[node*2+1];
  float sm0 = 0.f, sm1 = 0.f;
  for (int i = lane; i < deg; i += 64){
    int src = eb[i];
    float2 ev = *(const float2*)(esrc + (size_t)src * 2);
    float e0 = ev.x + ed0; e0 = e0 > 0.f ? e0 : 0.2f*e0;
    float e1 = ev.y + ed1; e1 = e1 > 0.f ? e1 : 0.2f*e1;
    float x0 = __expf(e0), x1 = __expf(e1);
    s_src[wv][i] = (unsigned short)src; s_x[wv][i] = make_float2(x0, x1);
    sm0 += x0; sm1 += x1;
  }
  #pragma unroll
  for (int off = 32; off > 0; off >>= 1){
    sm0 += __shfl_xor(sm0, off);
    sm1 += __shfl_xor(sm1, off);
  }
  float inv0 = 1.f / (sm0 + 1e-16f);
  float inv1 = 1.f / (sm1 + 1e-16f);
  int half = lane >> 5, hl = lane & 31;
  int c0 = hl * 8;
  int n0 = HOUT - c0; n0 = n0 < 0 ? 0 : (n0 > 8 ? 8 : n0);
  const __hip_bfloat16* __restrict__ hrow = h + c0;
  float acc[8] = {0.f,0.f,0.f,0.f,0.f,0.f,0.f,0.f};
  #define EDGE(IDX) { \
    bool vld = (IDX) < deg; \
    int jj = vld ? (IDX) : 0; \
    int s = s_src[wv][jj]; \
    float2 xv = s_x[wv][jj]; \
    float a0 = vld ? xv.x : 0.f; \
    float a1 = vld ? xv.y : 0.f; \
    uint4 d = *(const uint4*)(hrow + (size_t)s * HPAD); \
    acc[0] += (0 < n0 ? a0 : a1) * bflo(d.x); \
    acc[1] += (1 < n0 ? a0 : a1) * bfhi(d.x); \
    acc[2] += (2 < n0 ? a0 : a1) * bflo(d.y); \
    acc[3] += (3 < n0 ? a0 : a1) * bfhi(d.y); \
    acc[4] += (4 < n0 ? a0 : a1) * bflo(d.z); \
    acc[5] += (5 < n0 ? a0 : a1) * bfhi(d.z); \
    acc[6] += (6 < n0 ? a0 : a1) * bflo(d.w); \
    acc[7] += (7 < n0 ? a0 : a1) * bfhi(d.w); }
  for (int it = half; it < deg; it += 8){
    EDGE(it)
    EDGE(it + 2)
    EDGE(it + 4)
    EDGE(it + 6)
  }
  #undef EDGE
  #pragma unroll
  for (int j = 0; j < 8; ++j) acc[j] += __shfl_xor(acc[j], 32);
  if (half == 0){
    if (hl < 31){
      float4 bA = *(const float4*)&bias[c0];
      float4 bB = *(const float4*)&bias[c0 + 4];
      float v0 = acc[0]*(0 < n0 ? inv0 : inv1) + bA.x;
      float v1 = acc[1]*(1 < n0 ? inv0 : inv1) + bA.y;
      float v2 = acc[2]*(2 < n0 ? inv0 : inv1) + bA.z;
      float v3 = acc[3]*(3 < n0 ? inv0 : inv1) + bA.w;
      float v4 = acc[4]*(4 < n0 ? inv0 : inv1) + bB.x;
      float v5 = acc[5]*(5 < n0 ? inv0 : inv1) + bB.y;
      float v6 = acc[6]*(6 < n0 ? inv0 : inv1) + bB.z;
      float v7 = acc[7]*(7 < n0 ? inv0 : inv1) + bB.w;
      v0 = v0 > 0.f ? v0 : 0.f; v1 = v1 > 0.f ? v1 : 0.f;
      v2 = v2 > 0.f ? v2 : 0.f; v3 = v3 > 0.f ? v3 : 0.f;
      v4 = v4 > 0.f ? v4 : 0.f; v5 = v5 > 0.f ? v5 : 0.f;
      v6 = v6 > 0.f ? v6 : 0.f; v7 = v7 > 0.f ? v7 : 0.f;
      uint4 o;
      o.x = (unsigned int)f2bfbits(v0) | ((unsigned int)f2bfbits(v1) << 16);
      o.y = (unsigned int)f2bfbits(v2) | ((unsigned int)f2bfbits(v3) << 16);
      o.z = (unsigned int)f2bfbits(v4) | ((unsigned int)f2bfbits(v5) << 16);
      o.w = (unsigned int)f2bfbits(v6) | ((unsigned int)f2bfbits(v7) << 16);
      *(uint4*)(outb + (size_t)node * KP1 + c0) = o;
    } else {
      float v0 = acc[0]*inv1 + bias[248];
      float v1 = acc[1]*inv1 + bias[249];
      v0 = v0 > 0.f ? v0 : 0.f; v1 = v1 > 0.f ? v1 : 0.f;
      unsigned int o = (unsigned int)f2bfbits(v0) | ((unsigned int)f2bfbits(v1) << 16);
      *(unsigned int*)(outb + (size_t)node * KP1 + 248) = o;
    }
  }
}

// ---------------- fused head: segmented mean pool (bf16 input) + 4-layer MLP -----------
__global__ __launch_bounds__(256) void k_head(const __hip_bfloat16* __restrict__ xb,
                        const int* __restrict__ gstart,
                        const float* __restrict__ lw1, const float* __restrict__ lb1,
                        const float* __restrict__ lw2, const float* __restrict__ lb2,
                        const float* __restrict__ lw3, const float* __restrict__ lb3,
                        const float* __restrict__ lw4, const float* __restrict__ lb4,
                        float* __restrict__ out){
  int g = blockIdx.x;
  int tid = threadIdx.x;
  int s = gstart[g], e = gstart[g+1];
  __shared__ float gvec[256];
  __shared__ float m1[200];
  __shared__ float m2[112];
  __shared__ float m3[112];
  if (tid < 128){
    int c2 = tid * 2;
    const __hip_bfloat16* xp = xb + c2;
    float a0=0.f,a1=0.f,b0=0.f,b1=0.f;
    int n = s;
    for (; n + 3 < e; n += 4){
      unsigned int u0 = *(const unsigned int*)(xp + (size_t)n     * KP1);
      unsigned int u1 = *(const unsigned int*)(xp + (size_t)(n+1) * KP1);
      unsigned int u2 = *(const unsigned int*)(xp + (size_t)(n+2) * KP1);
      unsigned int u3 = *(const unsigned int*)(xp + (size_t)(n+3) * KP1);
      a0 += bflo(u0) + bflo(u2); a1 += bfhi(u0) + bfhi(u2);
      b0 += bflo(u1) + bflo(u3); b1 += bfhi(u1) + bfhi(u3);
    }
    for (; n < e; ++n){
      unsigned int u0 = *(const unsigned int*)(xp + (size_t)n * KP1);
      a0 += bflo(u0); a1 += bfhi(u0);
    }
    float scale = 1.f / fmaxf((float)(e - s), 1.f);
    gvec[c2]     = (a0 + b0) * scale;
    gvec[c2 + 1] = (a1 + b1) * scale;
  }
  __syncthreads();
  if (tid < 200){
    float a0=0.f,a1=0.f,a2=0.f,a3=0.f;
    int k = 0;
    for (; k + 3 < CH; k += 4){
      a0 += gvec[k]   * lw1[(size_t)k     * 200 + tid];
      a1 += gvec[k+1] * lw1[(size_t)(k+1) * 200 + tid];
      a2 += gvec[k+2] * lw1[(size_t)(k+2) * 200 + tid];
      a3 += gvec[k+3] * lw1[(size_t)(k+3) * 200 + tid];
    }
    for (; k < CH; ++k) a0 += gvec[k] * lw1[(size_t)k * 200 + tid];
    float v = a0 + a1 + a2 + a3 + lb1[tid];
    m1[tid] = v > 0.f ? v : 0.f;
  }
  __syncthreads();
  if (tid < 100){
    float a0=0.f,a1=0.f,a2=0.f,a3=0.f;
    for (int k = 0; k + 3 < 200; k += 4){
      a0 += m1[k]   * lw2[(size_t)k     * 100 + tid];
      a1 += m1[k+1] * lw2[(size_t)(k+1) * 100 + tid];
      a2 += m1[k+2] * lw2[(size_t)(k+2) * 100 + tid];
      a3 += m1[k+3] * lw2[(size_t)(k+3) * 100 + tid];
    }
    float v = a0 + a1 + a2 + a3 + lb2[tid];
    m2[tid] = v > 0.f ? v : 0.f;
  }
  __syncthreads();
  if (tid < 100){
    float a0=0.f,a1=0.f,a2=0.f,a3=0.f;
    for (int k = 0; k + 3 < 100; k += 4){
      a0 += m2[k]   * lw3[(size_t)k     * 100 + tid];
      a1 += m2[k+1] * lw3[(size_t)(k+1) * 100 + tid];
      a2 += m2[k+2] * lw3[(size_t)(k+2) * 100 + tid];
      a3 += m2[k+3] * lw3[(size_t)(k+3) * 100 + tid];
    }
    float v = a0 + a1 + a2 + a3 + lb3[tid];
    m3[tid] = v > 0.f ? v : 0.f;
  }
  __syncthreads();
  if (tid < 29){
    float a0=0.f,a1=0.f,a2=0.f,a3=0.f;
    for (int k = 0; k + 3 < 100; k += 4){
      a0 += m3[k]   * lw4[(size_t)k     * 29 + tid];
      a1 += m3[k+1] * lw4[(size_t)(k+1) * 29 + tid];
      a2 += m3[k+2] * lw4[(size_t)(k+2) * 29 + tid];
      a3 += m3[k+3] * lw4[(size_t)(k+3) * 29 + tid];
    }
    out[(size_t)g * 29 + tid] = a0 + a1 + a2 + a3 + lb4[tid];
  }
}

// ---------------- launch ----------------
extern "C" void kernel_launch(void* const* d_in, const int* in_sizes, int n_in,
                              void* d_out, int out_size, void* d_ws, size_t ws_size,
                              hipStream_t stream){
  char* ws = (char*)d_ws;
  size_t off = 0;
  auto alloc = [&](size_t bytes)->void*{
    void* p = ws + off;
    off = (off + bytes + 255) & ~(size_t)255;
    return p;
  };
  __hip_bfloat16* hb16A = (__hip_bfloat16*)alloc((size_t)NNODES * HPAD * 2);
  __hip_bfloat16* hb16B = (__hip_bfloat16*)alloc((size_t)NNODES * HPAD * 2);
  __hip_bfloat16* Abf0 = (__hip_bfloat16*)alloc((size_t)MPAD * KP0 * 2);
  __hip_bfloat16* Abf  = (__hip_bfloat16*)alloc((size_t)MPAD * KP1 * 2);
  __hip_bfloat16* Wt0  = (__hip_bfloat16*)alloc((size_t)16 * KP0 * 16 * 2);
  __hip_bfloat16* Wt1  = (__hip_bfloat16*)alloc((size_t)16 * KP1 * 16 * 2);
  __hip_bfloat16* Wt2  = (__hip_bfloat16*)alloc((size_t)16 * KP1 * 16 * 2);
  __hip_bfloat16* Wt3  = (__hip_bfloat16*)alloc((size_t)16 * KP1 * 16 * 2);
  size_t zbeg = off;
  int*   cursor = (int*)  alloc((size_t)NNODES * 4);      // doubles as deg
  float* esA  = (float*)alloc((size_t)NNODES * 2 * 4);    // layer-0 scores need zeroing
  float* edA  = (float*)alloc((size_t)NNODES * 2 * 4);
  size_t zend = off;
  float* esB  = (float*)alloc((size_t)NNODES * 2 * 4);    // plain-store targets
  float* edB  = (float*)alloc((size_t)NNODES * 2 * 4);
  unsigned short* bucket = (unsigned short*)alloc((size_t)NNODES * ECAP * 2);
  int*   gstart = (int*)alloc((size_t)(NGRAPH + 1) * 4);

  hipMemsetAsync(ws + zbeg, 0, zend - zbeg, stream);

  Args a;
  a.x = (const float*)d_in[0];
  a.eidx = (const int*)d_in[1];
  a.batch = (const int*)d_in[2];
  a.W0 = (const float*)d_in[3];  a.W1 = (const float*)d_in[7];
  a.W2 = (const float*)d_in[11]; a.W3 = (const float*)d_in[15];
  a.Abf0 = Abf0;
  a.Wt0 = Wt0; a.Wt1 = Wt1; a.Wt2 = Wt2; a.Wt3 = Wt3;
  a.cursor = cursor; a.bucket = bucket; a.gstart = gstart;

  k_pre<<<(ETOT + 255)/256, 256, 0, stream>>>(a);

  k_gemm<<<dim3(NTILE, 4), 256, 0, stream>>>(Abf0, Wt0, hb16A,
      (const float*)d_in[4], (const float*)d_in[5], esA, edA, KP0);

  k_fused<<<NNODES/16, 1024, 0, stream>>>(hb16A, esA, edA, cursor, bucket,
      (const float*)d_in[6],  Wt1, (const float*)d_in[8],  (const float*)d_in[9],
      hb16B, esB, edB);
  k_fused<<<NNODES/16, 1024, 0, stream>>>(hb16B, esB, edB, cursor, bucket,
      (const float*)d_in[10], Wt2, (const float*)d_in[12], (const float*)d_in[13],
      hb16A, esA, edA);
  k_fused<<<NNODES/16, 1024, 0, stream>>>(hb16A, esA, edA, cursor, bucket,
      (const float*)d_in[14], Wt3, (const float*)d_in[16], (const float*)d_in[17],
      hb16B, esB, edB);

  k_attn<<<NNODES/4, 256, 0, stream>>>(hb16B, esB, edB, cursor, bucket,
      (const float*)d_in[18], Abf);

  k_head<<<NGRAPH, 256, 0, stream>>>(Abf, gstart,
      (const float*)d_in[19], (const float*)d_in[20],
      (const float*)d_in[21], (const float*)d_in[22],
      (const float*)d_in[23], (const float*)d_in[24],
      (const float*)d_in[25], (const float*)d_in[26],
      (float*)d_out);
}